// Round 17
// baseline (84.752 us; speedup 1.0000x reference)
//
#include <hip/hip_runtime.h>
#include <hip/hip_bf16.h>
#include <math.h>

// Problem constants
#define B_  8
#define T_  2048
#define C_  128
#define H_  4
#define DH_ 32
#define BH_ 32
#define NTOK 16384
// (1/sqrt(32)) * log2(e): scores come out in log2 domain -> softmax via exp2
#define QSCALE_ 0.25503486f

// Fragment-blocked layouts: Kf/Qf/Vf[bh][blk][lane0..63][8 bf16]  (round 16)

typedef __attribute__((ext_vector_type(8))) __bf16 bfrag;        // 4 VGPRs, MFMA A/B
typedef __attribute__((ext_vector_type(4))) float f32x4;
typedef __attribute__((ext_vector_type(16))) float f32x16;       // 32x32 MFMA C/D
typedef __attribute__((ext_vector_type(2))) unsigned int u32x2;
typedef __attribute__((ext_vector_type(4))) unsigned int u32x4;

__device__ __forceinline__ unsigned int pack2bf(float a, float b) {
    unsigned int ua = __float_as_uint(a);
    unsigned int ub = __float_as_uint(b);
    ua += 0x7fffu + ((ua >> 16) & 1u);   // RNE to bf16
    ub += 0x7fffu + ((ub >> 16) & 1u);
    return (ua >> 16) | (ub & 0xffff0000u);
}

// single-instruction packed f32x2 -> bf16x2 (RNE; no builtin on gfx950)
__device__ __forceinline__ unsigned int cvtpk_bf16(float lo, float hi) {
    unsigned int r;
    asm("v_cvt_pk_bf16_f32 %0, %1, %2" : "=v"(r) : "v"(lo), "v"(hi));
    return r;
}

// raw v_exp_f32 (2^x)
__device__ __forceinline__ float fast_exp2(float x) {
    float r;
    asm("v_exp_f32 %0, %1" : "=v"(r) : "v"(x));
    return r;
}

// ---------------------------------------------------------------------------
// Kernel A: FUSED prep + QKV projection, one dispatch.
// Blocks 0..31: W transposes, then device-scope release-add on flag.
// Blocks 32..1055: spin on flag (all 1056 blocks are co-resident by
// construction: 4 waves, 0 LDS -> no deadlock regardless of dispatch order),
// then run the round-16 qkv_mfma body.
// ---------------------------------------------------------------------------
__global__ __launch_bounds__(256)
void prep_qkv(const float* __restrict__ x, const float* __restrict__ Wqkv,
              const float* __restrict__ bqkv, const float* __restrict__ Wout,
              __hip_bfloat16* __restrict__ WqkvT, __hip_bfloat16* __restrict__ WoutT,
              __hip_bfloat16* __restrict__ Qf, __hip_bfloat16* __restrict__ Kf,
              __hip_bfloat16* __restrict__ Vf, unsigned* __restrict__ flag) {
    const int bid = blockIdx.x;
    const int tid = threadIdx.x;

    if (bid < 32) {
        // ---- prep: W transposes (identical to round 16 prep)
        if (bid < 24) {
            const int idx = bid * 256 + tid;             // 0..6143
            const int n = idx >> 4, k8 = idx & 15;
            float v[8];
#pragma unroll
            for (int i = 0; i < 8; ++i) v[i] = Wqkv[(k8 * 8 + i) * 384 + n];
            u32x4 pk;
            pk.x = pack2bf(v[0], v[1]); pk.y = pack2bf(v[2], v[3]);
            pk.z = pack2bf(v[4], v[5]); pk.w = pack2bf(v[6], v[7]);
            *(u32x4*)(WqkvT + n * 128 + k8 * 8) = pk;
        } else {
            const int idx = (bid - 24) * 256 + tid;      // 0..2047
            const int n = idx >> 4, k8 = idx & 15;
            float v[8];
#pragma unroll
            for (int i = 0; i < 8; ++i) v[i] = Wout[(k8 * 8 + i) * 128 + n];
            u32x4 pk;
            pk.x = pack2bf(v[0], v[1]); pk.y = pack2bf(v[2], v[3]);
            pk.z = pack2bf(v[4], v[5]); pk.w = pack2bf(v[6], v[7]);
            *(u32x4*)(WoutT + n * 128 + k8 * 8) = pk;
        }
        __syncthreads();                  // all block stores issued (vmcnt drained)
        if (tid == 0) {
            __threadfence();              // device-scope writeback
            __hip_atomic_fetch_add(flag, 1u, __ATOMIC_RELEASE,
                                   __HIP_MEMORY_SCOPE_AGENT);
        }
        return;
    }

    // ---- wait for prep (acquire), then qkv (round-16 body, mbase shifted)
    if (tid == 0) {
        while (__hip_atomic_load(flag, __ATOMIC_ACQUIRE,
                                 __HIP_MEMORY_SCOPE_AGENT) < 32u)
            __builtin_amdgcn_s_sleep(8);
    }
    __syncthreads();

    const int mbase = (bid - 32) * 16;
    const int w = tid >> 6, lane = tid & 63;
    const int qi = lane & 15, grp = lane >> 4;

    const f32x4 zero = {0.f, 0.f, 0.f, 0.f};
    f32x4 acc[6] = {zero, zero, zero, zero, zero, zero};

    const float* xrow = x + (size_t)(mbase + qi) * 128;
    bfrag xf[4];
#pragma unroll
    for (int ks = 0; ks < 4; ++ks) {
        const float4 a = *(const float4*)(xrow + ks * 32 + grp * 8);
        const float4 b = *(const float4*)(xrow + ks * 32 + grp * 8 + 4);
        u32x4 pk;
        pk.x = cvtpk_bf16(a.x, a.y);
        pk.y = cvtpk_bf16(a.z, a.w);
        pk.z = cvtpk_bf16(b.x, b.y);
        pk.w = cvtpk_bf16(b.z, b.w);
        xf[ks] = __builtin_bit_cast(bfrag, pk);
    }

#pragma unroll
    for (int j = 0; j < 6; ++j) {
        const int nb = j * 4 + w;
#pragma unroll
        for (int ks = 0; ks < 4; ++ks) {
            const bfrag wf = *(const bfrag*)(WqkvT + (size_t)(nb * 16 + qi) * 128 + ks * 32 + grp * 8);
            if (j < 4) acc[j] = __builtin_amdgcn_mfma_f32_16x16x32_bf16(wf, xf[ks], acc[j], 0, 0, 0);
            else       acc[j] = __builtin_amdgcn_mfma_f32_16x16x32_bf16(xf[ks], wf, acc[j], 0, 0, 0);
        }
    }

    const long bb = mbase >> 11;        // batch
    const long tloc = mbase & 2047;     // token within batch

    // Q/K: lane owns token t, regs = 4 consecutive d (d0 % 4 == 0)
#pragma unroll
    for (int j = 0; j < 4; ++j) {
        const int nb = j * 4 + w;
        const int c0 = nb * 16 + grp * 4;
        const float4 bias = *(const float4*)&bqkv[c0];
        const int local = c0 & 127;
        const int h = local >> 5, d0 = local & 31;
        __hip_bfloat16* dst = (j < 2) ? Qf : Kf;
        const float sc = (j < 2) ? QSCALE_ : 1.f;
        const long t = tloc + qi;              // token within batch (0..2047)
        const long bh = bb * H_ + h;
        const long blk = (bh * 64 + (t >> 5)) * 2 + (d0 >> 4);
        const int lanei = (int)(t & 31) + ((d0 & 15) >> 3) * 32;
        u32x2 pw;
        pw.x = pack2bf((acc[j][0] + bias.x) * sc, (acc[j][1] + bias.y) * sc);
        pw.y = pack2bf((acc[j][2] + bias.z) * sc, (acc[j][3] + bias.w) * sc);
        *(u32x2*)&dst[blk * 512 + lanei * 8 + (d0 & 7)] = pw;
    }
    // V: lane owns row d, regs = 4 consecutive s (s0 % 4 == 0)
#pragma unroll
    for (int j = 4; j < 6; ++j) {
        const int nb = j * 4 + w;
        const int c = nb * 16 + qi;
        const int local = c - 256;
        const int h = local >> 5, d = local & 31;
        const float bias = bqkv[c];
        const long t0 = tloc + grp * 4;        // s token (0..2047)
        const long bh = bb * H_ + h;
        const int s0 = (int)(t0 & 31);
        const long blk = (bh * 64 + (t0 >> 5)) * 2 + (s0 >> 4);
        const int lanei = d + ((s0 & 15) >> 3) * 32;
        u32x2 pw;
        pw.x = pack2bf(acc[j][0] + bias, acc[j][1] + bias);
        pw.y = pack2bf(acc[j][2] + bias, acc[j][3] + bias);
        *(u32x2*)&Vf[blk * 512 + lanei * 8 + (s0 & 7)] = pw;
    }
}

// ---------------------------------------------------------------------------
// Kernel B: FUSED attention + out-projection (round 16 verbatim).
// ---------------------------------------------------------------------------
__global__ __launch_bounds__(512, 4)
void attn_out(const __hip_bfloat16* __restrict__ Qf,
              const __hip_bfloat16* __restrict__ Kf,
              const __hip_bfloat16* __restrict__ Vf,
              const __hip_bfloat16* __restrict__ WoutT,
              const float* __restrict__ bout, float* __restrict__ out) {
    __shared__ float csm[4][64][17];       // parity-1 partials (17.4 KB)
    __shared__ unsigned int Osm[32][68];   // bf16-pair rows (8.7 KB)

    const int lin = blockIdx.x;            // 0..511
    int b, c;
    if (lin < 256) { b = lin & 7; c = 63 - (lin >> 3); }     // heavy half
    else { const int m = lin - 256; b = m & 7; c = m >> 3; } // light half

    const int w    = threadIdx.x >> 6;     // 0..7
    const int h    = w & 3;                // head
    const int e    = w >> 2;               // s-parity
    const int lane = threadIdx.x & 63;
    const int ql   = lane & 31;
    const int hi   = lane >> 5;
    const int hi4  = hi * 4;

    const int bh = b * H_ + h;
    const int q  = c * 32 + ql;

    const __hip_bfloat16* Qp = Qf + (size_t)bh * 64 * 1024;
    const __hip_bfloat16* Kp = Kf + (size_t)bh * 64 * 1024;
    const __hip_bfloat16* Vp = Vf + (size_t)bh * 64 * 1024;

    const bfrag qf0 = *(const bfrag*)(Qp + (c * 2 + 0) * 512 + lane * 8);
    const bfrag qf1 = *(const bfrag*)(Qp + (c * 2 + 1) * 512 + lane * 8);

    f32x16 o;
#pragma unroll
    for (int r = 0; r < 16; ++r) o[r] = 0.f;
    float l = 0.f;

    auto ldK = [&](int u, bfrag& k0, bfrag& k1, bfrag& v0, bfrag& v1) {
        k0 = *(const bfrag*)(Kp + (u * 2 + 0) * 512 + lane * 8);
        k1 = *(const bfrag*)(Kp + (u * 2 + 1) * 512 + lane * 8);
        v0 = *(const bfrag*)(Vp + (u * 2 + 0) * 512 + lane * 8);
        v1 = *(const bfrag*)(Vp + (u * 2 + 1) * 512 + lane * 8);
    };

    auto proc = [&](const bfrag& kf0, const bfrag& kf1, const bfrag& vf0,
                    const bfrag& vf1, int sbase, bool band) {
        f32x16 s;
#pragma unroll
        for (int r = 0; r < 16; ++r) s[r] = 0.f;
        s = __builtin_amdgcn_mfma_f32_32x32x16_bf16(kf0, qf0, s, 0, 0, 0);
        s = __builtin_amdgcn_mfma_f32_32x32x16_bf16(kf1, qf1, s, 0, 0, 0);
        if (band) {
#pragma unroll
            for (int r = 0; r < 16; ++r) {
                const int srow = sbase + (r & 3) + 8 * (r >> 2) + hi4;
                if (srow > q) s[r] = -INFINITY;
            }
        }
#pragma unroll
        for (int r = 0; r < 16; ++r) { s[r] = fast_exp2(s[r]); l += s[r]; }
        u32x4 w0, w1;
        {
            unsigned a0 = cvtpk_bf16(s[0], s[1]);
            unsigned a1 = cvtpk_bf16(s[2], s[3]);
            unsigned a2 = cvtpk_bf16(s[4], s[5]);
            unsigned a3 = cvtpk_bf16(s[6], s[7]);
            auto r02 = __builtin_amdgcn_permlane32_swap((int)a0, (int)a2, false, false);
            auto r13 = __builtin_amdgcn_permlane32_swap((int)a1, (int)a3, false, false);
            w0.x = (unsigned)r02[0]; w0.y = (unsigned)r13[0];
            w0.z = (unsigned)r02[1]; w0.w = (unsigned)r13[1];
        }
        {
            unsigned a0 = cvtpk_bf16(s[8],  s[9]);
            unsigned a1 = cvtpk_bf16(s[10], s[11]);
            unsigned a2 = cvtpk_bf16(s[12], s[13]);
            unsigned a3 = cvtpk_bf16(s[14], s[15]);
            auto r02 = __builtin_amdgcn_permlane32_swap((int)a0, (int)a2, false, false);
            auto r13 = __builtin_amdgcn_permlane32_swap((int)a1, (int)a3, false, false);
            w1.x = (unsigned)r02[0]; w1.y = (unsigned)r13[0];
            w1.z = (unsigned)r02[1]; w1.w = (unsigned)r13[1];
        }
        o = __builtin_amdgcn_mfma_f32_32x32x16_bf16(
                vf0, __builtin_bit_cast(bfrag, w0), o, 0, 0, 0);
        o = __builtin_amdgcn_mfma_f32_32x32x16_bf16(
                vf1, __builtin_bit_cast(bfrag, w1), o, 0, 0, 0);
    };

    // ---- attention over units u = e, e+2, ... <= c (2-deep ping-pong)
    if (e <= c) {
        bfrag ck0, ck1, cv0, cv1, nk0, nk1, nv0, nv1;
        ldK(e, ck0, ck1, cv0, cv1);
        for (int u = e; u <= c; u += 2) {
            if (u + 2 <= c) ldK(u + 2, nk0, nk1, nv0, nv1);
            proc(ck0, ck1, cv0, cv1, u * 32, u == c);
            ck0 = nk0; ck1 = nk1; cv0 = nv0; cv1 = nv1;
        }
    }

    // merge the two hi-halves' l (same q, disjoint s rows)
    l += __shfl_xor(l, 32);

    // ---- parity combine (fixed-max softmax -> plain sums)
    if (e == 1) {
        float* my = &csm[h][lane][0];
        f32x4 t0 = {o[0], o[1], o[2], o[3]};
        f32x4 t1 = {o[4], o[5], o[6], o[7]};
        f32x4 t2 = {o[8], o[9], o[10], o[11]};
        f32x4 t3 = {o[12], o[13], o[14], o[15]};
        *(f32x4*)(my + 0) = t0;  *(f32x4*)(my + 4) = t1;
        *(f32x4*)(my + 8) = t2;  *(f32x4*)(my + 12) = t3;
        my[16] = l;
    }
    __syncthreads();
    if (e == 0) {
        const float* pr = &csm[h][lane][0];
#pragma unroll
        for (int r = 0; r < 16; ++r) o[r] += pr[r];
        l += pr[16];
        const float rl = 1.f / l;
#pragma unroll
        for (int pi = 0; pi < 8; ++pi) {
            const int r = pi * 2;
            const int n = (r & 3) + 8 * (r >> 2) + hi4;      // dim within head
            Osm[ql][(h * 32 + n) >> 1] = cvtpk_bf16(o[r] * rl, o[r + 1] * rl);
        }
    }
    __syncthreads();

    // ---- output projection by the 4 e==0 waves: wave h -> cols h*32..+31
    if (e == 0) {
        const int hi8 = hi * 8;
        f32x16 acc;
#pragma unroll
        for (int r = 0; r < 16; ++r) acc[r] = 0.f;
#pragma unroll
        for (int ks = 0; ks < 8; ++ks) {
            const bfrag wf = *(const bfrag*)(WoutT + (size_t)(h * 32 + ql) * 128 + ks * 16 + hi8);
            const u32x4 ofu = *(const u32x4*)&Osm[ql][ks * 8 + hi4];
            acc = __builtin_amdgcn_mfma_f32_32x32x16_bf16(
                      wf, __builtin_bit_cast(bfrag, ofu), acc, 0, 0, 0);
        }
        float* orow = out + ((size_t)b * T_ + c * 32 + ql) * 128 + h * 32;
#pragma unroll
        for (int pi = 0; pi < 8; ++pi) {
            const int r = pi * 2;
            const int n = (r & 3) + 8 * (r >> 2) + hi4;
            const float2 bb2 = *(const float2*)&bout[h * 32 + n];
            float2 ov;
            ov.x = acc[r] + bb2.x;
            ov.y = acc[r + 1] + bb2.y;
            *(float2*)&orow[n] = ov;
        }
    }
}

// ---------------------------------------------------------------------------
extern "C" void kernel_launch(void* const* d_in, const int* in_sizes, int n_in,
                              void* d_out, int out_size, void* d_ws, size_t ws_size,
                              hipStream_t stream) {
    const float* x    = (const float*)d_in[0];
    const float* Wqkv = (const float*)d_in[1];
    const float* bqkv = (const float*)d_in[2];
    const float* Wout = (const float*)d_in[3];
    const float* bout = (const float*)d_in[4];
    float* out = (float*)d_out;

    const size_t per = (size_t)BH_ * T_ * DH_;   // 2,097,152 bf16 elems = 4 MB
    __hip_bfloat16* Qf    = (__hip_bfloat16*)d_ws;
    __hip_bfloat16* Kf    = Qf + per;
    __hip_bfloat16* Vf    = Kf + per;
    __hip_bfloat16* WqkvT = Vf + per;
    __hip_bfloat16* WoutT = WqkvT + 384 * 128;

    unsigned* flag = (unsigned*)((char*)d_ws + (32u << 20));
    hipMemsetAsync(flag, 0, 4, stream);

    prep_qkv<<<1056, 256, 0, stream>>>(x, Wqkv, bqkv, Wout,
                                       WqkvT, WoutT, Qf, Kf, Vf, flag);

    attn_out<<<512, 512, 0, stream>>>(Qf, Kf, Vf, WoutT, bout, out);
}

// Round 18
// 41.231 us; speedup vs baseline: 2.0556x; 2.0556x over previous
//
#include <hip/hip_runtime.h>
#include <hip/hip_bf16.h>
#include <math.h>

// Problem constants
#define B_  8
#define T_  2048
#define C_  128
#define H_  4
#define DH_ 32
#define BH_ 32
#define NTOK 16384
// (1/sqrt(32)) * log2(e): scores come out in log2 domain -> softmax via exp2
#define QSCALE_ 0.25503486f

// Fragment-blocked global layouts (round 16): Qf/Kf/Vf[bh][blk][lane][8 bf16]

typedef __attribute__((ext_vector_type(8))) __bf16 bfrag;        // 4 VGPRs, MFMA A/B
typedef __attribute__((ext_vector_type(4))) float f32x4;
typedef __attribute__((ext_vector_type(16))) float f32x16;       // 32x32 MFMA C/D
typedef __attribute__((ext_vector_type(2))) unsigned int u32x2;
typedef __attribute__((ext_vector_type(4))) unsigned int u32x4;

__device__ __forceinline__ unsigned int pack2bf(float a, float b) {
    unsigned int ua = __float_as_uint(a);
    unsigned int ub = __float_as_uint(b);
    ua += 0x7fffu + ((ua >> 16) & 1u);   // RNE to bf16
    ub += 0x7fffu + ((ub >> 16) & 1u);
    return (ua >> 16) | (ub & 0xffff0000u);
}

// single-instruction packed f32x2 -> bf16x2 (RNE; no builtin on gfx950)
__device__ __forceinline__ unsigned int cvtpk_bf16(float lo, float hi) {
    unsigned int r;
    asm("v_cvt_pk_bf16_f32 %0, %1, %2" : "=v"(r) : "v"(lo), "v"(hi));
    return r;
}

// raw v_exp_f32 (2^x)
__device__ __forceinline__ float fast_exp2(float x) {
    float r;
    asm("v_exp_f32 %0, %1" : "=v"(r) : "v"(x));
    return r;
}

// ---------------------------------------------------------------------------
// Kernel 1: FUSED W-transpose + QKV projection (prep kernel eliminated).
// Grid 256 x 256 thr, 64 tokens/block. Each block transposes ALL of Wqkv
// (fp32 [128][384]) into fragment-blocked LDS (nb 0..23, ks 0..3: frag
// [64 lanes][8 bf16], lane-contiguous -> conflict-free ds_read_b128), then
// each wave runs the round-16 MFMA body for its 16 tokens over nb = 0..23
// sequentially (acc = one f32x4). Store mapping identical to round 16.
// ---------------------------------------------------------------------------
__global__ __launch_bounds__(256)
void qkv_fused(const float* __restrict__ x, const float* __restrict__ Wqkv,
               const float* __restrict__ bqkv,
               __hip_bfloat16* __restrict__ Qf, __hip_bfloat16* __restrict__ Kf,
               __hip_bfloat16* __restrict__ Vf) {
    __shared__ __hip_bfloat16 Wl[24 * 4 * 64 * 8];   // 49152 elems = 96 KB
    const int tid = threadIdx.x;

    // ---- transpose Wqkv -> frag-blocked LDS (96 u32 writes/thread)
    unsigned* Wlu = (unsigned*)Wl;
#pragma unroll 4
    for (int j = 0; j < 96; ++j) {
        const int i = j * 256 + tid;       // pair index: kk*384 + n
        const int kk = i / 384;            // k-pair 0..63
        const int n  = i - kk * 384;       // 0..383
        const float lo = Wqkv[(2 * kk) * 384 + n];
        const float hi = Wqkv[(2 * kk + 1) * 384 + n];
        const int k = 2 * kk;
        const int nb = n >> 4, qi_ = n & 15;
        const int ks = k >> 5, grp_ = (k >> 3) & 3, off = k & 7;
        Wlu[(((nb * 4 + ks) * 64) + grp_ * 16 + qi_) * 4 + (off >> 1)] = cvtpk_bf16(lo, hi);
    }
    __syncthreads();

    // ---- per-wave QKV body (16 tokens/wave)
    const int w = tid >> 6, lane = tid & 63;
    const int qi = lane & 15, grp = lane >> 4;
    const int mbase = blockIdx.x * 64 + w * 16;

    const float* xrow = x + (size_t)(mbase + qi) * 128;
    bfrag xf[4];
#pragma unroll
    for (int ks = 0; ks < 4; ++ks) {
        const float4 a = *(const float4*)(xrow + ks * 32 + grp * 8);
        const float4 b = *(const float4*)(xrow + ks * 32 + grp * 8 + 4);
        u32x4 pk;
        pk.x = cvtpk_bf16(a.x, a.y);
        pk.y = cvtpk_bf16(a.z, a.w);
        pk.z = cvtpk_bf16(b.x, b.y);
        pk.w = cvtpk_bf16(b.z, b.w);
        xf[ks] = __builtin_bit_cast(bfrag, pk);
    }

    const long bb = mbase >> 11;        // batch
    const long tloc = mbase & 2047;     // token within batch
    const f32x4 zero = {0.f, 0.f, 0.f, 0.f};

#pragma unroll
    for (int nb = 0; nb < 24; ++nb) {
        f32x4 a = zero;
#pragma unroll
        for (int ks = 0; ks < 4; ++ks) {
            const bfrag wf = *(const bfrag*)&Wl[((nb * 4 + ks) * 64 + lane) * 8];
            if (nb < 16) a = __builtin_amdgcn_mfma_f32_16x16x32_bf16(wf, xf[ks], a, 0, 0, 0);
            else         a = __builtin_amdgcn_mfma_f32_16x16x32_bf16(xf[ks], wf, a, 0, 0, 0);
        }
        if (nb < 16) {
            // Q/K: lane owns token t, regs = 4 consecutive d (d0 % 4 == 0)
            const int c0 = nb * 16 + grp * 4;
            const float4 bias = *(const float4*)&bqkv[c0];
            const int local = c0 & 127;
            const int h = local >> 5, d0 = local & 31;
            __hip_bfloat16* dst = (nb < 8) ? Qf : Kf;
            const float sc = (nb < 8) ? QSCALE_ : 1.f;
            const long t = tloc + qi;
            const long bh = bb * H_ + h;
            const long blk = (bh * 64 + (t >> 5)) * 2 + (d0 >> 4);
            const int lanei = (int)(t & 31) + ((d0 & 15) >> 3) * 32;
            u32x2 pw;
            pw.x = pack2bf((a[0] + bias.x) * sc, (a[1] + bias.y) * sc);
            pw.y = pack2bf((a[2] + bias.z) * sc, (a[3] + bias.w) * sc);
            *(u32x2*)&dst[blk * 512 + lanei * 8 + (d0 & 7)] = pw;
        } else {
            // V: lane owns row d, regs = 4 consecutive s (s0 % 4 == 0)
            const int c = nb * 16 + qi;
            const int local = c - 256;
            const int h = local >> 5, d = local & 31;
            const float bias = bqkv[c];
            const long t0 = tloc + grp * 4;
            const long bh = bb * H_ + h;
            const int s0 = (int)(t0 & 31);
            const long blk = (bh * 64 + (t0 >> 5)) * 2 + (s0 >> 4);
            const int lanei = d + ((s0 & 15) >> 3) * 32;
            u32x2 pw;
            pw.x = pack2bf(a[0] + bias, a[1] + bias);
            pw.y = pack2bf(a[2] + bias, a[3] + bias);
            *(u32x2*)&Vf[blk * 512 + lanei * 8 + (s0 & 7)] = pw;
        }
    }
}

// ---------------------------------------------------------------------------
// Kernel 2: FUSED attention + out-projection (round 16 verbatim) + in-kernel
// Wout transpose into frag-blocked LDS (prep dependency removed).
// Block = (b, chunk c); 8 waves = 4 heads x 2 s-parities. Grid 512 x 512.
// LDS: Wo 32 KB + csm 17.4 KB + Osm 8.7 KB = 58 KB -> 2 blocks/CU.
// ---------------------------------------------------------------------------
__global__ __launch_bounds__(512, 4)
void attn_out(const __hip_bfloat16* __restrict__ Qf,
              const __hip_bfloat16* __restrict__ Kf,
              const __hip_bfloat16* __restrict__ Vf,
              const float* __restrict__ Wout,
              const float* __restrict__ bout, float* __restrict__ out) {
    __shared__ float csm[4][64][17];        // parity-1 partials (17.4 KB)
    __shared__ unsigned int Osm[32][68];    // bf16-pair rows (8.7 KB)
    __shared__ __hip_bfloat16 Wo[32 * 64 * 8];  // frag-blocked WoutT (32 KB)

    const int lin = blockIdx.x;            // 0..511
    int b, c;
    if (lin < 256) { b = lin & 7; c = 63 - (lin >> 3); }     // heavy half
    else { const int m = lin - 256; b = m & 7; c = m >> 3; } // light half

    // ---- transpose Wout (fp32 [128][128]) -> frag-blocked LDS (16 u32/thread)
    {
        unsigned* Wou = (unsigned*)Wo;
#pragma unroll
        for (int j = 0; j < 16; ++j) {
            const int i = j * 512 + threadIdx.x;   // pair index kk*128 + n
            const int kk = i >> 7;                 // 0..63
            const int n  = i & 127;
            const float lo = Wout[(2 * kk) * 128 + n];
            const float hi = Wout[(2 * kk + 1) * 128 + n];
            const int k = 2 * kk;
            const int hh = n >> 5, qn = n & 31;
            const int ks = k >> 4, hib = (k >> 3) & 1, off = k & 7;
            Wou[(((hh * 8 + ks) * 64) + hib * 32 + qn) * 4 + (off >> 1)] = cvtpk_bf16(lo, hi);
        }
    }
    // (ordering: Wo is read only after the two __syncthreads below)

    const int w    = threadIdx.x >> 6;     // 0..7
    const int h    = w & 3;                // head
    const int e    = w >> 2;               // s-parity
    const int lane = threadIdx.x & 63;
    const int ql   = lane & 31;
    const int hi   = lane >> 5;
    const int hi4  = hi * 4;

    const int bh = b * H_ + h;
    const int q  = c * 32 + ql;

    const __hip_bfloat16* Qp = Qf + (size_t)bh * 64 * 1024;
    const __hip_bfloat16* Kp = Kf + (size_t)bh * 64 * 1024;
    const __hip_bfloat16* Vp = Vf + (size_t)bh * 64 * 1024;

    const bfrag qf0 = *(const bfrag*)(Qp + (c * 2 + 0) * 512 + lane * 8);
    const bfrag qf1 = *(const bfrag*)(Qp + (c * 2 + 1) * 512 + lane * 8);

    f32x16 o;
#pragma unroll
    for (int r = 0; r < 16; ++r) o[r] = 0.f;
    float l = 0.f;

    auto ldK = [&](int u, bfrag& k0, bfrag& k1, bfrag& v0, bfrag& v1) {
        k0 = *(const bfrag*)(Kp + (u * 2 + 0) * 512 + lane * 8);
        k1 = *(const bfrag*)(Kp + (u * 2 + 1) * 512 + lane * 8);
        v0 = *(const bfrag*)(Vp + (u * 2 + 0) * 512 + lane * 8);
        v1 = *(const bfrag*)(Vp + (u * 2 + 1) * 512 + lane * 8);
    };

    auto proc = [&](const bfrag& kf0, const bfrag& kf1, const bfrag& vf0,
                    const bfrag& vf1, int sbase, bool band) {
        f32x16 s;
#pragma unroll
        for (int r = 0; r < 16; ++r) s[r] = 0.f;
        s = __builtin_amdgcn_mfma_f32_32x32x16_bf16(kf0, qf0, s, 0, 0, 0);
        s = __builtin_amdgcn_mfma_f32_32x32x16_bf16(kf1, qf1, s, 0, 0, 0);
        if (band) {
#pragma unroll
            for (int r = 0; r < 16; ++r) {
                const int srow = sbase + (r & 3) + 8 * (r >> 2) + hi4;
                if (srow > q) s[r] = -INFINITY;
            }
        }
#pragma unroll
        for (int r = 0; r < 16; ++r) { s[r] = fast_exp2(s[r]); l += s[r]; }
        u32x4 w0, w1;
        {
            unsigned a0 = cvtpk_bf16(s[0], s[1]);
            unsigned a1 = cvtpk_bf16(s[2], s[3]);
            unsigned a2 = cvtpk_bf16(s[4], s[5]);
            unsigned a3 = cvtpk_bf16(s[6], s[7]);
            auto r02 = __builtin_amdgcn_permlane32_swap((int)a0, (int)a2, false, false);
            auto r13 = __builtin_amdgcn_permlane32_swap((int)a1, (int)a3, false, false);
            w0.x = (unsigned)r02[0]; w0.y = (unsigned)r13[0];
            w0.z = (unsigned)r02[1]; w0.w = (unsigned)r13[1];
        }
        {
            unsigned a0 = cvtpk_bf16(s[8],  s[9]);
            unsigned a1 = cvtpk_bf16(s[10], s[11]);
            unsigned a2 = cvtpk_bf16(s[12], s[13]);
            unsigned a3 = cvtpk_bf16(s[14], s[15]);
            auto r02 = __builtin_amdgcn_permlane32_swap((int)a0, (int)a2, false, false);
            auto r13 = __builtin_amdgcn_permlane32_swap((int)a1, (int)a3, false, false);
            w1.x = (unsigned)r02[0]; w1.y = (unsigned)r13[0];
            w1.z = (unsigned)r02[1]; w1.w = (unsigned)r13[1];
        }
        o = __builtin_amdgcn_mfma_f32_32x32x16_bf16(
                vf0, __builtin_bit_cast(bfrag, w0), o, 0, 0, 0);
        o = __builtin_amdgcn_mfma_f32_32x32x16_bf16(
                vf1, __builtin_bit_cast(bfrag, w1), o, 0, 0, 0);
    };

    // ---- attention over units u = e, e+2, ... <= c (2-deep ping-pong)
    if (e <= c) {
        bfrag ck0, ck1, cv0, cv1, nk0, nk1, nv0, nv1;
        ldK(e, ck0, ck1, cv0, cv1);
        for (int u = e; u <= c; u += 2) {
            if (u + 2 <= c) ldK(u + 2, nk0, nk1, nv0, nv1);
            proc(ck0, ck1, cv0, cv1, u * 32, u == c);
            ck0 = nk0; ck1 = nk1; cv0 = nv0; cv1 = nv1;
        }
    }

    // merge the two hi-halves' l (same q, disjoint s rows)
    l += __shfl_xor(l, 32);

    // ---- parity combine (fixed-max softmax -> plain sums)
    if (e == 1) {
        float* my = &csm[h][lane][0];
        f32x4 t0 = {o[0], o[1], o[2], o[3]};
        f32x4 t1 = {o[4], o[5], o[6], o[7]};
        f32x4 t2 = {o[8], o[9], o[10], o[11]};
        f32x4 t3 = {o[12], o[13], o[14], o[15]};
        *(f32x4*)(my + 0) = t0;  *(f32x4*)(my + 4) = t1;
        *(f32x4*)(my + 8) = t2;  *(f32x4*)(my + 12) = t3;
        my[16] = l;
    }
    __syncthreads();
    if (e == 0) {
        const float* pr = &csm[h][lane][0];
#pragma unroll
        for (int r = 0; r < 16; ++r) o[r] += pr[r];
        l += pr[16];
        const float rl = 1.f / l;
#pragma unroll
        for (int pi = 0; pi < 8; ++pi) {
            const int r = pi * 2;
            const int n = (r & 3) + 8 * (r >> 2) + hi4;      // dim within head
            Osm[ql][(h * 32 + n) >> 1] = cvtpk_bf16(o[r] * rl, o[r + 1] * rl);
        }
    }
    __syncthreads();

    // ---- output projection by the 4 e==0 waves: wave h -> cols h*32..+31
    if (e == 0) {
        f32x16 acc;
#pragma unroll
        for (int r = 0; r < 16; ++r) acc[r] = 0.f;
#pragma unroll
        for (int ks = 0; ks < 8; ++ks) {
            const bfrag wf = *(const bfrag*)&Wo[((h * 8 + ks) * 64 + lane) * 8];
            const u32x4 ofu = *(const u32x4*)&Osm[ql][ks * 8 + hi4];
            acc = __builtin_amdgcn_mfma_f32_32x32x16_bf16(
                      wf, __builtin_bit_cast(bfrag, ofu), acc, 0, 0, 0);
        }
        float* orow = out + ((size_t)b * T_ + c * 32 + ql) * 128 + h * 32;
#pragma unroll
        for (int pi = 0; pi < 8; ++pi) {
            const int r = pi * 2;
            const int n = (r & 3) + 8 * (r >> 2) + hi4;
            const float2 bb2 = *(const float2*)&bout[h * 32 + n];
            float2 ov;
            ov.x = acc[r] + bb2.x;
            ov.y = acc[r + 1] + bb2.y;
            *(float2*)&orow[n] = ov;
        }
    }
}

// ---------------------------------------------------------------------------
extern "C" void kernel_launch(void* const* d_in, const int* in_sizes, int n_in,
                              void* d_out, int out_size, void* d_ws, size_t ws_size,
                              hipStream_t stream) {
    const float* x    = (const float*)d_in[0];
    const float* Wqkv = (const float*)d_in[1];
    const float* bqkv = (const float*)d_in[2];
    const float* Wout = (const float*)d_in[3];
    const float* bout = (const float*)d_in[4];
    float* out = (float*)d_out;

    const size_t per = (size_t)BH_ * T_ * DH_;   // 2,097,152 bf16 elems = 4 MB
    __hip_bfloat16* Qf = (__hip_bfloat16*)d_ws;
    __hip_bfloat16* Kf = Qf + per;
    __hip_bfloat16* Vf = Kf + per;

    qkv_fused<<<256, 256, 0, stream>>>(x, Wqkv, bqkv, Qf, Kf, Vf);

    attn_out<<<512, 512, 0, stream>>>(Qf, Kf, Vf, Wout, bout, out);
}

// Round 19
// 37.491 us; speedup vs baseline: 2.2606x; 1.0997x over previous
//
#include <hip/hip_runtime.h>
#include <hip/hip_bf16.h>
#include <math.h>

// Problem constants
#define B_  8
#define T_  2048
#define C_  128
#define H_  4
#define DH_ 32
#define BH_ 32
#define NTOK 16384
// (1/sqrt(32)) * log2(e): scores come out in log2 domain -> softmax via exp2
#define QSCALE_ 0.25503486f

// Fragment-blocked global layouts (round 16): Qf/Kf/Vf[bh][blk][lane][8 bf16]

typedef __attribute__((ext_vector_type(8))) __bf16 bfrag;        // 4 VGPRs, MFMA A/B
typedef __attribute__((ext_vector_type(4))) float f32x4;
typedef __attribute__((ext_vector_type(16))) float f32x16;       // 32x32 MFMA C/D
typedef __attribute__((ext_vector_type(2))) unsigned int u32x2;
typedef __attribute__((ext_vector_type(4))) unsigned int u32x4;

__device__ __forceinline__ unsigned int pack2bf(float a, float b) {
    unsigned int ua = __float_as_uint(a);
    unsigned int ub = __float_as_uint(b);
    ua += 0x7fffu + ((ua >> 16) & 1u);   // RNE to bf16
    ub += 0x7fffu + ((ub >> 16) & 1u);
    return (ua >> 16) | (ub & 0xffff0000u);
}

// single-instruction packed f32x2 -> bf16x2 (RNE; no builtin on gfx950)
__device__ __forceinline__ unsigned int cvtpk_bf16(float lo, float hi) {
    unsigned int r;
    asm("v_cvt_pk_bf16_f32 %0, %1, %2" : "=v"(r) : "v"(lo), "v"(hi));
    return r;
}

// raw v_exp_f32 (2^x)
__device__ __forceinline__ float fast_exp2(float x) {
    float r;
    asm("v_exp_f32 %0, %1" : "=v"(r) : "v"(x));
    return r;
}

// ---------------------------------------------------------------------------
// Kernel 1: QKV projection, blocks SPECIALIZED by output third (Q/K/V).
// bid>>8: 0=Q, 1=K, 2=V. Each block transposes only its 128-col third of
// Wqkv into 32 KB frag-blocked LDS (~5 blocks/CU -> 20 waves/CU vs round
// 18's 4), then runs the proven MFMA body for 64 tokens over 8 n-blocks.
// Store mapping identical to round 18 (nb = kind*8 + nbl).
// ---------------------------------------------------------------------------
__global__ __launch_bounds__(256)
void qkv_part(const float* __restrict__ x, const float* __restrict__ Wqkv,
              const float* __restrict__ bqkv,
              __hip_bfloat16* __restrict__ Qf, __hip_bfloat16* __restrict__ Kf,
              __hip_bfloat16* __restrict__ Vf) {
    __shared__ __hip_bfloat16 Wl[8 * 4 * 64 * 8];   // 16384 elems = 32 KB
    const int bid  = blockIdx.x;        // 0..767
    const int kind = bid >> 8;          // 0=Q, 1=K, 2=V
    const int tb   = bid & 255;         // token block
    const int tid  = threadIdx.x;
    const int cbase = kind << 7;

    // ---- transpose this third of Wqkv -> frag-blocked LDS (32 u32/thread)
    unsigned* Wlu = (unsigned*)Wl;
#pragma unroll
    for (int j = 0; j < 32; ++j) {
        const int i  = j * 256 + tid;    // pair index: kk*128 + nl
        const int kk = i >> 7;           // k-pair 0..63
        const int nl = i & 127;
        const float lo = Wqkv[(2 * kk) * 384 + cbase + nl];
        const float hi = Wqkv[(2 * kk + 1) * 384 + cbase + nl];
        const int k = 2 * kk;
        const int nb = nl >> 4, qi_ = nl & 15;
        const int ks = k >> 5, grp_ = (k >> 3) & 3;
        Wlu[(((nb * 4 + ks) * 64) + grp_ * 16 + qi_) * 4 + ((k & 7) >> 1)] = cvtpk_bf16(lo, hi);
    }
    __syncthreads();

    // ---- per-wave MFMA body (16 tokens/wave)
    const int w = tid >> 6, lane = tid & 63;
    const int qi = lane & 15, grp = lane >> 4;
    const int mbase = tb * 64 + w * 16;

    const float* xrow = x + (size_t)(mbase + qi) * 128;
    bfrag xf[4];
#pragma unroll
    for (int ks = 0; ks < 4; ++ks) {
        const float4 a = *(const float4*)(xrow + ks * 32 + grp * 8);
        const float4 b = *(const float4*)(xrow + ks * 32 + grp * 8 + 4);
        u32x4 pk;
        pk.x = cvtpk_bf16(a.x, a.y);
        pk.y = cvtpk_bf16(a.z, a.w);
        pk.z = cvtpk_bf16(b.x, b.y);
        pk.w = cvtpk_bf16(b.z, b.w);
        xf[ks] = __builtin_bit_cast(bfrag, pk);
    }

    const long bb = mbase >> 11;        // batch
    const long tloc = mbase & 2047;     // token within batch
    const f32x4 zero = {0.f, 0.f, 0.f, 0.f};

#pragma unroll
    for (int nbl = 0; nbl < 8; ++nbl) {
        const int nb = kind * 8 + nbl;
        f32x4 a = zero;
#pragma unroll
        for (int ks = 0; ks < 4; ++ks) {
            const bfrag wf = *(const bfrag*)&Wl[((nbl * 4 + ks) * 64 + lane) * 8];
            if (kind < 2) a = __builtin_amdgcn_mfma_f32_16x16x32_bf16(wf, xf[ks], a, 0, 0, 0);
            else          a = __builtin_amdgcn_mfma_f32_16x16x32_bf16(xf[ks], wf, a, 0, 0, 0);
        }
        if (kind < 2) {
            // Q/K: lane owns token t, regs = 4 consecutive d (d0 % 4 == 0)
            const int c0 = nb * 16 + grp * 4;
            const float4 bias = *(const float4*)&bqkv[c0];
            const int local = c0 & 127;
            const int h = local >> 5, d0 = local & 31;
            __hip_bfloat16* dst = (kind == 0) ? Qf : Kf;
            const float sc = (kind == 0) ? QSCALE_ : 1.f;
            const long t = tloc + qi;
            const long bh = bb * H_ + h;
            const long blk = (bh * 64 + (t >> 5)) * 2 + (d0 >> 4);
            const int lanei = (int)(t & 31) + ((d0 & 15) >> 3) * 32;
            u32x2 pw;
            pw.x = pack2bf((a[0] + bias.x) * sc, (a[1] + bias.y) * sc);
            pw.y = pack2bf((a[2] + bias.z) * sc, (a[3] + bias.w) * sc);
            *(u32x2*)&dst[blk * 512 + lanei * 8 + (d0 & 7)] = pw;
        } else {
            // V: lane owns row d, regs = 4 consecutive s (s0 % 4 == 0)
            const int c = nb * 16 + qi;
            const int local = c - 256;
            const int h = local >> 5, d = local & 31;
            const float bias = bqkv[c];
            const long t0 = tloc + grp * 4;
            const long bh = bb * H_ + h;
            const int s0 = (int)(t0 & 31);
            const long blk = (bh * 64 + (t0 >> 5)) * 2 + (s0 >> 4);
            const int lanei = d + ((s0 & 15) >> 3) * 32;
            u32x2 pw;
            pw.x = pack2bf(a[0] + bias, a[1] + bias);
            pw.y = pack2bf(a[2] + bias, a[3] + bias);
            *(u32x2*)&Vf[blk * 512 + lanei * 8 + (s0 & 7)] = pw;
        }
    }
}

// ---------------------------------------------------------------------------
// Kernel 2: FUSED attention + out-projection (round 18 structure) with VALU
// trims: z16 hoisted (MFMA C reads zero regs directly, no per-proc re-init);
// explicit 2-body ping-pong (no fragment reg copies); tree-sum for l.
// Block = (b, chunk c); 8 waves = 4 heads x 2 s-parities. Grid 512 x 512.
// ---------------------------------------------------------------------------
__global__ __launch_bounds__(512, 4)
void attn_out(const __hip_bfloat16* __restrict__ Qf,
              const __hip_bfloat16* __restrict__ Kf,
              const __hip_bfloat16* __restrict__ Vf,
              const float* __restrict__ Wout,
              const float* __restrict__ bout, float* __restrict__ out) {
    __shared__ float csm[4][64][17];        // parity-1 partials (17.4 KB)
    __shared__ unsigned int Osm[32][68];    // bf16-pair rows (8.7 KB)
    __shared__ __hip_bfloat16 Wo[32 * 64 * 8];  // frag-blocked WoutT (32 KB)

    const int lin = blockIdx.x;            // 0..511
    int b, c;
    if (lin < 256) { b = lin & 7; c = 63 - (lin >> 3); }     // heavy half
    else { const int m = lin - 256; b = m & 7; c = m >> 3; } // light half

    // ---- transpose Wout (fp32 [128][128]) -> frag-blocked LDS (16 u32/thread)
    {
        unsigned* Wou = (unsigned*)Wo;
#pragma unroll
        for (int j = 0; j < 16; ++j) {
            const int i = j * 512 + threadIdx.x;   // pair index kk*128 + n
            const int kk = i >> 7;                 // 0..63
            const int n  = i & 127;
            const float lo = Wout[(2 * kk) * 128 + n];
            const float hi = Wout[(2 * kk + 1) * 128 + n];
            const int k = 2 * kk;
            const int hh = n >> 5, qn = n & 31;
            const int ks = k >> 4, hib = (k >> 3) & 1;
            Wou[(((hh * 8 + ks) * 64) + hib * 32 + qn) * 4 + ((k & 7) >> 1)] = cvtpk_bf16(lo, hi);
        }
    }

    const int w    = threadIdx.x >> 6;     // 0..7
    const int h    = w & 3;                // head
    const int e    = w >> 2;               // s-parity
    const int lane = threadIdx.x & 63;
    const int ql   = lane & 31;
    const int hi   = lane >> 5;
    const int hi4  = hi * 4;

    const int bh = b * H_ + h;
    const int q  = c * 32 + ql;

    const __hip_bfloat16* Qp = Qf + (size_t)bh * 64 * 1024;
    const __hip_bfloat16* Kp = Kf + (size_t)bh * 64 * 1024;
    const __hip_bfloat16* Vp = Vf + (size_t)bh * 64 * 1024;

    const bfrag qf0 = *(const bfrag*)(Qp + (c * 2 + 0) * 512 + lane * 8);
    const bfrag qf1 = *(const bfrag*)(Qp + (c * 2 + 1) * 512 + lane * 8);

    f32x16 o, z16;
#pragma unroll
    for (int r = 0; r < 16; ++r) { o[r] = 0.f; z16[r] = 0.f; }
    float l = 0.f;

    auto ldK = [&](int u, bfrag& k0, bfrag& k1, bfrag& v0, bfrag& v1) {
        k0 = *(const bfrag*)(Kp + (u * 2 + 0) * 512 + lane * 8);
        k1 = *(const bfrag*)(Kp + (u * 2 + 1) * 512 + lane * 8);
        v0 = *(const bfrag*)(Vp + (u * 2 + 0) * 512 + lane * 8);
        v1 = *(const bfrag*)(Vp + (u * 2 + 1) * 512 + lane * 8);
    };

    auto proc = [&](const bfrag& kf0, const bfrag& kf1, const bfrag& vf0,
                    const bfrag& vf1, int sbase, bool band) {
        f32x16 s = __builtin_amdgcn_mfma_f32_32x32x16_bf16(kf0, qf0, z16, 0, 0, 0);
        s = __builtin_amdgcn_mfma_f32_32x32x16_bf16(kf1, qf1, s, 0, 0, 0);
        if (band) {
#pragma unroll
            for (int r = 0; r < 16; ++r) {
                const int srow = sbase + (r & 3) + 8 * (r >> 2) + hi4;
                if (srow > q) s[r] = -INFINITY;
            }
        }
#pragma unroll
        for (int r = 0; r < 16; ++r) s[r] = fast_exp2(s[r]);
        // tree-sum into l (short dependency chains)
        {
            float t0 = (s[0] + s[1]) + (s[2] + s[3]);
            float t1 = (s[4] + s[5]) + (s[6] + s[7]);
            float t2 = (s[8] + s[9]) + (s[10] + s[11]);
            float t3 = (s[12] + s[13]) + (s[14] + s[15]);
            l += (t0 + t1) + (t2 + t3);
        }
        u32x4 w0, w1;
        {
            unsigned a0 = cvtpk_bf16(s[0], s[1]);
            unsigned a1 = cvtpk_bf16(s[2], s[3]);
            unsigned a2 = cvtpk_bf16(s[4], s[5]);
            unsigned a3 = cvtpk_bf16(s[6], s[7]);
            auto r02 = __builtin_amdgcn_permlane32_swap((int)a0, (int)a2, false, false);
            auto r13 = __builtin_amdgcn_permlane32_swap((int)a1, (int)a3, false, false);
            w0.x = (unsigned)r02[0]; w0.y = (unsigned)r13[0];
            w0.z = (unsigned)r02[1]; w0.w = (unsigned)r13[1];
        }
        {
            unsigned a0 = cvtpk_bf16(s[8],  s[9]);
            unsigned a1 = cvtpk_bf16(s[10], s[11]);
            unsigned a2 = cvtpk_bf16(s[12], s[13]);
            unsigned a3 = cvtpk_bf16(s[14], s[15]);
            auto r02 = __builtin_amdgcn_permlane32_swap((int)a0, (int)a2, false, false);
            auto r13 = __builtin_amdgcn_permlane32_swap((int)a1, (int)a3, false, false);
            w1.x = (unsigned)r02[0]; w1.y = (unsigned)r13[0];
            w1.z = (unsigned)r02[1]; w1.w = (unsigned)r13[1];
        }
        o = __builtin_amdgcn_mfma_f32_32x32x16_bf16(
                vf0, __builtin_bit_cast(bfrag, w0), o, 0, 0, 0);
        o = __builtin_amdgcn_mfma_f32_32x32x16_bf16(
                vf1, __builtin_bit_cast(bfrag, w1), o, 0, 0, 0);
    };

    // ---- attention over units u = e, e+2, ... <= c, explicit ping-pong
    if (e <= c) {
        bfrag ak0, ak1, av0, av1, bk0, bk1, bv0, bv1;
        int u = e;
        ldK(u, ak0, ak1, av0, av1);
        while (true) {
            if (u + 2 <= c) ldK(u + 2, bk0, bk1, bv0, bv1);
            proc(ak0, ak1, av0, av1, u * 32, u == c);
            u += 2;
            if (u > c) break;
            if (u + 2 <= c) ldK(u + 2, ak0, ak1, av0, av1);
            proc(bk0, bk1, bv0, bv1, u * 32, u == c);
            u += 2;
            if (u > c) break;
        }
    }

    // merge the two hi-halves' l (same q, disjoint s rows)
    l += __shfl_xor(l, 32);

    // ---- parity combine (fixed-max softmax -> plain sums)
    if (e == 1) {
        float* my = &csm[h][lane][0];
        f32x4 t0 = {o[0], o[1], o[2], o[3]};
        f32x4 t1 = {o[4], o[5], o[6], o[7]};
        f32x4 t2 = {o[8], o[9], o[10], o[11]};
        f32x4 t3 = {o[12], o[13], o[14], o[15]};
        *(f32x4*)(my + 0) = t0;  *(f32x4*)(my + 4) = t1;
        *(f32x4*)(my + 8) = t2;  *(f32x4*)(my + 12) = t3;
        my[16] = l;
    }
    __syncthreads();
    if (e == 0) {
        const float* pr = &csm[h][lane][0];
#pragma unroll
        for (int r = 0; r < 16; ++r) o[r] += pr[r];
        l += pr[16];
        const float rl = 1.f / l;
#pragma unroll
        for (int pi = 0; pi < 8; ++pi) {
            const int r = pi * 2;
            const int n = (r & 3) + 8 * (r >> 2) + hi4;      // dim within head
            Osm[ql][(h * 32 + n) >> 1] = cvtpk_bf16(o[r] * rl, o[r + 1] * rl);
        }
    }
    __syncthreads();

    // ---- output projection by the 4 e==0 waves: wave h -> cols h*32..+31
    if (e == 0) {
        f32x16 acc;
#pragma unroll
        for (int r = 0; r < 16; ++r) acc[r] = 0.f;
#pragma unroll
        for (int ks = 0; ks < 8; ++ks) {
            const bfrag wf = *(const bfrag*)&Wo[((h * 8 + ks) * 64 + lane) * 8];
            const u32x4 ofu = *(const u32x4*)&Osm[ql][ks * 8 + hi4];
            acc = __builtin_amdgcn_mfma_f32_32x32x16_bf16(
                      wf, __builtin_bit_cast(bfrag, ofu), acc, 0, 0, 0);
        }
        float* orow = out + ((size_t)b * T_ + c * 32 + ql) * 128 + h * 32;
#pragma unroll
        for (int pi = 0; pi < 8; ++pi) {
            const int r = pi * 2;
            const int n = (r & 3) + 8 * (r >> 2) + hi4;
            const float2 bb2 = *(const float2*)&bout[h * 32 + n];
            float2 ov;
            ov.x = acc[r] + bb2.x;
            ov.y = acc[r + 1] + bb2.y;
            *(float2*)&orow[n] = ov;
        }
    }
}

// ---------------------------------------------------------------------------
extern "C" void kernel_launch(void* const* d_in, const int* in_sizes, int n_in,
                              void* d_out, int out_size, void* d_ws, size_t ws_size,
                              hipStream_t stream) {
    const float* x    = (const float*)d_in[0];
    const float* Wqkv = (const float*)d_in[1];
    const float* bqkv = (const float*)d_in[2];
    const float* Wout = (const float*)d_in[3];
    const float* bout = (const float*)d_in[4];
    float* out = (float*)d_out;

    const size_t per = (size_t)BH_ * T_ * DH_;   // 2,097,152 bf16 elems = 4 MB
    __hip_bfloat16* Qf = (__hip_bfloat16*)d_ws;
    __hip_bfloat16* Kf = Qf + per;
    __hip_bfloat16* Vf = Kf + per;

    qkv_part<<<768, 256, 0, stream>>>(x, Wqkv, bqkv, Qf, Kf, Vf);

    attn_out<<<512, 512, 0, stream>>>(Qf, Kf, Vf, Wout, bout, out);
}